// Round 11
// baseline (213.698 us; speedup 1.0000x reference)
//
#include <hip/hip_runtime.h>
#include <hip/hip_fp16.h>

#define BN_EPS 1e-5f
#define BUCKET 20000   // nodes per bucket (80 KB f32 LDS in scatter -> 2 WG/CU)

typedef int      v4i __attribute__((ext_vector_type(4)));
typedef unsigned v2u __attribute__((ext_vector_type(2)));
typedef float    v4f __attribute__((ext_vector_type(4)));
typedef unsigned long long u64;

__device__ __forceinline__ __half2 u2h2(unsigned u) {
    union { unsigned u; __half2 h; } c; c.u = u; return c.h;
}

// scale/shift from raw stats
__device__ __forceinline__ float2 bn_params(const double* acc,
                                            const float* bnw,
                                            const float* bnb, int E) {
    double mean = acc[0] / (double)E;
    double var  = acc[1] / (double)E - mean * mean;
    float scale = bnw[0] * rsqrtf((float)var + BN_EPS);
    float shift = bnb[0] - (float)mean * scale;
    return make_float2(scale, shift);
}

// ---------------------------------------------------------------------------
// K0: pack BOTH f32 [N][12] tables into fp16 [N][16] (32 B aligned rows).
// ---------------------------------------------------------------------------
__global__ void k_pack_both(const float* __restrict__ src_emb,
                            const float* __restrict__ dst_emb,
                            __half2* __restrict__ hs,
                            __half2* __restrict__ hd, int N) {
    int t = blockIdx.x * blockDim.x + threadIdx.x;
    if (t >= 2 * N) return;
    int n = (t < N) ? t : t - N;
    const float* r = ((t < N) ? src_emb : dst_emb) + (size_t)n * 12;
    __half2* hemb = (t < N) ? hs : hd;
    union { int4 v[2]; __half2 h[8]; } u;
    #pragma unroll
    for (int k = 0; k < 6; ++k) u.h[k] = __floats2half2_rn(r[2 * k], r[2 * k + 1]);
    u.h[6] = __floats2half2_rn(0.f, 0.f);
    u.h[7] = u.h[6];
    int4* dst = (int4*)(hemb + (size_t)n * 8);
    dst[0] = u.v[0];
    dst[1] = u.v[1];
}

__device__ __forceinline__ float rowdot(const int4* __restrict__ a,
                                        const int4* __restrict__ b) {
    union U { int4 v; unsigned u[4]; };
    U a0{a[0]}, a1{a[1]}, b0{b[0]}, b1{b[1]};
    unsigned au[6] = {a0.u[0], a0.u[1], a0.u[2], a0.u[3], a1.u[0], a1.u[1]};
    unsigned bu[6] = {b0.u[0], b0.u[1], b0.u[2], b0.u[3], b1.u[0], b1.u[1]};
    float dot = 0.f;
    #pragma unroll
    for (int k = 0; k < 6; ++k) {
        float2 fa = __half22float2(u2h2(au[k]));
        float2 fb = __half22float2(u2h2(bu[k]));
        dot = fmaf(fa.x, fb.x, dot);
        dot = fmaf(fa.y, fb.y, dot);
    }
    return dot;
}

// pack/unpack pair: [eid:22 | gsrc:17 | like-fp16:16]  (55 bits)
__device__ __forceinline__ u64 pack_pair(int eid, int gs, float dot) {
    unsigned h = (unsigned)__half_as_ushort(__float2half(dot));
    return ((u64)(unsigned)eid << 33) | ((u64)(unsigned)gs << 16) | (u64)h;
}

// ---------------------------------------------------------------------------
// K1: bucketed gather-dot. Block (g,p): stream edge slice g (NT), keep edges
// with gsrc in bucket p; gather hs slice (0.64 MB, L2-resident) + hd
// (3.2 MB, L2-resident); dot; append packed pair to dense region via
// ballot-aggregated LDS counter; exact block stats -> double atomics.
// blockIdx.x = g runs fastest -> all XCDs process bucket p in the same
// temporal phase (hs slice hot in every L2).
// ---------------------------------------------------------------------------
__global__ __launch_bounds__(256) void k_dot_bucket(
        const __half2* __restrict__ hs,
        const __half2* __restrict__ hd,
        const int* __restrict__ gsrc,
        const int* __restrict__ gdst,
        u64* __restrict__ pairs,
        int* __restrict__ cnt,
        double* __restrict__ acc,
        int E, int G, int cap) {
    const int g  = blockIdx.x;
    const int p  = blockIdx.y;
    const int lo = p * BUCKET;
    __shared__ unsigned s_cnt;
    if (threadIdx.x == 0) s_cnt = 0;
    __syncthreads();

    int per = (E + G - 1) / G;
    per = (per + 3) & ~3;
    const int s0 = g * per;
    const int s1 = min(s0 + per, E);
    u64* region = pairs + (size_t)(p * G + g) * cap;

    const int lane = threadIdx.x & 63;
    const u64 lt_mask = (lane == 63) ? ~0ULL >> 1 : (1ULL << lane) - 1;

    float lsum = 0.f, lsq = 0.f;

    for (int e = s0 + (int)threadIdx.x * 4; e < s1; e += (int)blockDim.x * 4) {
        if (e + 4 <= s1) {
            v4i s4 = __builtin_nontemporal_load((const v4i*)(gsrc + e));
            v4i d4 = __builtin_nontemporal_load((const v4i*)(gdst + e));
            int is[4] = {s4.x, s4.y, s4.z, s4.w};
            int id[4] = {d4.x, d4.y, d4.z, d4.w};
            #pragma unroll
            for (int k = 0; k < 4; ++k) {
                bool mem = (unsigned)(is[k] - lo) < (unsigned)BUCKET;
                u64 m = __ballot(mem);
                if (m) {
                    int leader = __ffsll((long long)m) - 1;
                    unsigned base = 0;
                    if (lane == leader)
                        base = atomicAdd(&s_cnt, (unsigned)__popcll(m));
                    base = __shfl(base, leader);
                    if (mem) {
                        float dot = rowdot((const int4*)(hs + (size_t)is[k] * 8),
                                           (const int4*)(hd + (size_t)id[k] * 8));
                        lsum += dot;
                        lsq  = fmaf(dot, dot, lsq);
                        unsigned slot = base + (unsigned)__popcll(m & lt_mask);
                        if (slot < (unsigned)cap)
                            region[slot] = pack_pair(e + k, is[k], dot);
                    }
                }
            }
        } else {
            for (int k = 0; e + k < s1; ++k) {
                int gs = gsrc[e + k];
                if ((unsigned)(gs - lo) < (unsigned)BUCKET) {
                    float dot = rowdot((const int4*)(hs + (size_t)gs * 8),
                                       (const int4*)(hd + (size_t)gdst[e + k] * 8));
                    lsum += dot;
                    lsq  += dot * dot;
                    unsigned slot = atomicAdd(&s_cnt, 1u);
                    if (slot < (unsigned)cap)
                        region[slot] = pack_pair(e + k, gs, dot);
                }
            }
        }
    }

    for (int off = 32; off > 0; off >>= 1) {
        lsum += __shfl_down(lsum, off);
        lsq  += __shfl_down(lsq, off);
    }
    __shared__ float ssum[4], ssq[4];
    int wave = threadIdx.x >> 6;
    if (lane == 0) { ssum[wave] = lsum; ssq[wave] = lsq; }
    __syncthreads();
    if (threadIdx.x == 0) {
        float ts = 0.f, tq = 0.f;
        for (int i = 0; i < 4; ++i) { ts += ssum[i]; tq += ssq[i]; }
        atomicAdd(&acc[0], (double)ts);
        atomicAdd(&acc[1], (double)tq);
        cnt[p * G + g] = (int)min(s_cnt, (unsigned)cap);
    }
}

// ---------------------------------------------------------------------------
// K3: single-visit scatter. Block (g3,p) reads R=G/G3 pair regions of its
// bucket (dense, counts known), LDS-atomicAdds exp(like*s+t), flushes one
// slab replica. No membership waste, no idx/like re-reads.
// ---------------------------------------------------------------------------
__global__ __launch_bounds__(512) void k_pair_scatter(
        const u64* __restrict__ pairs,
        const int* __restrict__ cnt,
        const double* __restrict__ acc,
        const float* __restrict__ bnw,
        const float* __restrict__ bnb,
        float* __restrict__ slab,   // [(p*G3 + g3) * BUCKET]
        int E, int G, int G3, int cap) {
    extern __shared__ float sm[];
    __shared__ float2 s_par;
    const int g3 = blockIdx.x;
    const int p  = blockIdx.y;
    const int lo = p * BUCKET;
    if (threadIdx.x == 0) s_par = bn_params(acc, bnw, bnb, E);
    for (int i = threadIdx.x; i < BUCKET; i += blockDim.x) sm[i] = 0.f;
    __syncthreads();
    const float scale = s_par.x;
    const float shift = s_par.y;

    const int R = G / G3;
    for (int r = 0; r < R; ++r) {
        int rid = p * G + g3 * R + r;
        int n = cnt[rid];
        const u64* reg = pairs + (size_t)rid * cap;
        for (int i = threadIdx.x; i < n; i += blockDim.x) {
            u64 pk = reg[i];
            int gs = (int)((pk >> 16) & 0x1FFFF);
            float l = __half2float(__ushort_as_half((unsigned short)(pk & 0xFFFF)));
            atomicAdd(&sm[gs - lo], __expf(fmaf(l, scale, shift)));
        }
    }
    __syncthreads();

    float* dst = slab + ((size_t)p * G3 + g3) * BUCKET;
    for (int i = threadIdx.x; i < BUCKET; i += blockDim.x)
        __builtin_nontemporal_store(sm[i], dst + i);
}

// ---------------------------------------------------------------------------
// K3b: fold slabs: denom[n] = sum_g3 slab[(p(n)*G3 + g3)*BUCKET + n%BUCKET]
// ---------------------------------------------------------------------------
__global__ void k_fold(const float* __restrict__ slab,
                       float* __restrict__ denom, int N, int G3) {
    int n = blockIdx.x * blockDim.x + threadIdx.x;
    if (n >= N) return;
    int p   = n / BUCKET;
    int off = n - p * BUCKET;
    const float* s = slab + (size_t)p * G3 * BUCKET + off;
    float acc = 0.f;
    for (int g = 0; g < G3; ++g)
        acc += __builtin_nontemporal_load(s + (size_t)g * BUCKET);
    denom[n] = acc;
}

// ---------------------------------------------------------------------------
// K4: normalize from pair stream: out[eid] = exp(l*s+t)/(1e-12+denom[gs]).
// denom is 400 KB -> L2-resident. out writes are mostly-ascending per region.
// ---------------------------------------------------------------------------
__global__ __launch_bounds__(256) void k_norm_pairs(
        const u64* __restrict__ pairs,
        const int* __restrict__ cnt,
        const double* __restrict__ acc,
        const float* __restrict__ bnw,
        const float* __restrict__ bnb,
        const float* __restrict__ denom,
        float* __restrict__ out,
        int E, int G, int cap) {
    __shared__ float2 s_par;
    if (threadIdx.x == 0) s_par = bn_params(acc, bnw, bnb, E);
    __syncthreads();
    const float scale = s_par.x;
    const float shift = s_par.y;
    int rid = blockIdx.y * G + blockIdx.x;
    int n = cnt[rid];
    const u64* reg = pairs + (size_t)rid * cap;
    for (int i = threadIdx.x; i < n; i += blockDim.x) {
        u64 pk = reg[i];
        int eid = (int)(pk >> 33);
        int gs  = (int)((pk >> 16) & 0x1FFFF);
        float l = __half2float(__ushort_as_half((unsigned short)(pk & 0xFFFF)));
        out[eid] = __expf(fmaf(l, scale, shift)) / (1e-12f + denom[gs]);
    }
}

// ------------------------- fallback path (generic) -------------------------
__global__ __launch_bounds__(256) void k_dot_fused(
        const __half2* __restrict__ hs, const __half2* __restrict__ hd,
        const int* __restrict__ gsrc, const int* __restrict__ gdst,
        __half* __restrict__ like, double* __restrict__ acc, int E) {
    int e0 = (blockIdx.x * blockDim.x + threadIdx.x) * 8;
    float lsum = 0.f, lsq = 0.f;
    for (int e = e0; e < min(e0 + 8, E); ++e) {
        float d = rowdot((const int4*)(hs + (size_t)gsrc[e] * 8),
                         (const int4*)(hd + (size_t)gdst[e] * 8));
        like[e] = __float2half(d);
        lsum += d; lsq += d * d;
    }
    for (int off = 32; off > 0; off >>= 1) {
        lsum += __shfl_down(lsum, off);
        lsq  += __shfl_down(lsq, off);
    }
    __shared__ float ssum[4], ssq[4];
    int wave = threadIdx.x >> 6, lane = threadIdx.x & 63;
    if (lane == 0) { ssum[wave] = lsum; ssq[wave] = lsq; }
    __syncthreads();
    if (threadIdx.x == 0) {
        float ts = 0.f, tq = 0.f;
        for (int i = 0; i < 4; ++i) { ts += ssum[i]; tq += ssq[i]; }
        atomicAdd(&acc[0], (double)ts);
        atomicAdd(&acc[1], (double)tq);
    }
}
__global__ void k_exp_scatter_agent(const __half* __restrict__ like,
                                    const int* __restrict__ gsrc,
                                    const double* __restrict__ acc,
                                    const float* __restrict__ bnw,
                                    const float* __restrict__ bnb,
                                    float* __restrict__ denom, int E) {
    __shared__ float2 s_par;
    if (threadIdx.x == 0) s_par = bn_params(acc, bnw, bnb, E);
    __syncthreads();
    for (int e = blockIdx.x * blockDim.x + threadIdx.x; e < E;
         e += gridDim.x * blockDim.x)
        atomicAdd(&denom[gsrc[e]],
                  __expf(fmaf(__half2float(like[e]), s_par.x, s_par.y)));
}
__global__ void k_normalize_edge(const __half* __restrict__ like,
                                 const int* __restrict__ gsrc,
                                 const double* __restrict__ acc,
                                 const float* __restrict__ bnw,
                                 const float* __restrict__ bnb,
                                 const float* __restrict__ denom,
                                 float* __restrict__ out, int E) {
    __shared__ float2 s_par;
    if (threadIdx.x == 0) s_par = bn_params(acc, bnw, bnb, E);
    __syncthreads();
    int e = blockIdx.x * blockDim.x + threadIdx.x;
    if (e < E)
        out[e] = __expf(fmaf(__half2float(like[e]), s_par.x, s_par.y)) /
                 (1e-12f + denom[gsrc[e]]);
}

extern "C" void kernel_launch(void* const* d_in, const int* in_sizes, int n_in,
                              void* d_out, int out_size, void* d_ws, size_t ws_size,
                              hipStream_t stream) {
    const float* src_emb = (const float*)d_in[0];
    const float* dst_emb = (const float*)d_in[1];
    const float* bnw     = (const float*)d_in[2];
    const float* bnb     = (const float*)d_in[3];
    const int*   gsrc    = (const int*)d_in[4];
    const int*   gdst    = (const int*)d_in[5];

    const int E = in_sizes[4];           // 3,200,000 edges
    const int N = in_sizes[0] / 12;      // 100,000 nodes
    float* out = (float*)d_out;

    const int P  = (N + BUCKET - 1) / BUCKET;   // 5 buckets
    const int G  = 128;                          // dot slices
    const int G3 = 64;                           // scatter replicas (G % G3 == 0)

    int per = (E + G - 1) / G;
    per = (per + 3) & ~3;
    // region capacity: mean + huge margin (>>15 sigma for uniform random)
    int cap = (int)((double)per * BUCKET / (double)N * 1.25) + 256;
    cap = (cap + 15) & ~15;

    // workspace layout (64B-aligned)
    char* ws = (char*)d_ws;
    double* acc   = (double*)ws;
    size_t  off   = 64;
    int*    cnt   = (int*)(ws + off);    off += ((size_t)G * P * 4 + 63) & ~(size_t)63;
    float*  denom = (float*)(ws + off);  off += ((size_t)N * 4 + 63) & ~(size_t)63;
    __half2* hs   = (__half2*)(ws + off); off += ((size_t)N * 32 + 63) & ~(size_t)63;
    __half2* hd   = (__half2*)(ws + off); off += ((size_t)N * 32 + 63) & ~(size_t)63;
    float*  slab  = (float*)(ws + off);  off += ((size_t)P * G3 * BUCKET * 4 + 63) & ~(size_t)63;
    u64*    pairs = (u64*)(ws + off);
    size_t need = off + (size_t)G * P * cap * 8;

    const int block = 256;
    bool fast = (E < (1 << 22)) && (N < (1 << 17)) && (need <= ws_size);

    hipMemsetAsync(ws, 0, 32, stream);
    k_pack_both<<<(2 * N + block - 1) / block, block, 0, stream>>>(
        src_emb, dst_emb, hs, hd, N);

    if (fast) {
        dim3 gdot(G, P);
        k_dot_bucket<<<gdot, block, 0, stream>>>(hs, hd, gsrc, gdst,
                                                 pairs, cnt, acc, E, G, cap);
        dim3 gsc(G3, P);
        k_pair_scatter<<<gsc, 512, (size_t)BUCKET * 4, stream>>>(
            pairs, cnt, acc, bnw, bnb, slab, E, G, G3, cap);
        k_fold<<<(N + block - 1) / block, block, 0, stream>>>(slab, denom, N, G3);
        dim3 gnm(G, P);
        k_norm_pairs<<<gnm, block, 0, stream>>>(pairs, cnt, acc, bnw, bnb,
                                                denom, out, E, G, cap);
    } else {
        __half* like = (__half*)pairs;   // reuse region
        int b8 = (E / 8 + block - 1) / block + 1;
        k_dot_fused<<<b8, block, 0, stream>>>(hs, hd, gsrc, gdst, like, acc, E);
        hipMemsetAsync(denom, 0, (size_t)N * 4, stream);
        int blocks = min((E + block - 1) / block, 4096);
        k_exp_scatter_agent<<<blocks, block, 0, stream>>>(like, gsrc, acc,
                                                          bnw, bnb, denom, E);
        k_normalize_edge<<<(E + block - 1) / block, block, 0, stream>>>(
            like, gsrc, acc, bnw, bnb, denom, out, E);
    }
}